// Round 9
// baseline (2054.003 us; speedup 1.0000x reference)
//
#include <hip/hip_runtime.h>
#include <hip/hip_bf16.h>

// CharRNN: 2-layer LSTM LM + softmax CE on MI355X (gfx950).
// Round 9: flag-gated dataflow recurrence (per-producer ready flags, bulk
// sc1 data loads, no sentinel re-polling), input projection folded into the
// recurrence (x-part MFMAs hide in the poll window; gemm1/G1 eliminated),
// CE at 8 waves/block for 2x SIMD occupancy.
// dims: V=8000, B=64, T=128, H=512.

#define V_SIZE 8000
#define B_SIZE 64
#define T_SIZE 128
#define H_SIZE 512
#define NROW   (B_SIZE * T_SIZE)     // 8192
#define NG     (4 * H_SIZE)          // 2048 gate columns
#define HB     (H_SIZE * B_SIZE)     // one h time-slice (bf16 elems)
#define RBLK   64                    // recurrence grid (merged blocks)
#define RTH    256                   // recurrence block size

typedef __attribute__((ext_vector_type(8))) short bf16x8;
typedef __attribute__((ext_vector_type(8))) unsigned short u16x8;
typedef __attribute__((ext_vector_type(4))) float f32x4;

// ---------- bf16 helpers (raw ushort storage) ----------
__device__ __forceinline__ float bf2f(unsigned short u) {
  union { unsigned int i; float f; } x; x.i = ((unsigned int)u) << 16; return x.f;
}
__device__ __forceinline__ unsigned short f2bf(float f) {
  union { float f; unsigned int i; } x; x.f = f;
  unsigned int r = x.i + 0x7fffu + ((x.i >> 16) & 1u);
  return (unsigned short)(r >> 16);
}
__device__ __forceinline__ float sigf(float v) { return 1.f / (1.f + __expf(-v)); }
__device__ __forceinline__ float tanhf_fast(float v) {
  return 1.f - 2.f / (__expf(2.f * v) + 1.f);
}

// agent-scope (MALL-coherent) 16B A-fragment load as 2x u64
__device__ __forceinline__ bf16x8 aload16(const unsigned short* p) {
  unsigned long long lo = __hip_atomic_load((const unsigned long long*)p,
                                            __ATOMIC_RELAXED, __HIP_MEMORY_SCOPE_AGENT);
  unsigned long long hi = __hip_atomic_load((const unsigned long long*)(p + 4),
                                            __ATOMIC_RELAXED, __HIP_MEMORY_SCOPE_AGENT);
  union { unsigned long long v[2]; bf16x8 b; } u;
  u.v[0] = lo; u.v[1] = hi;
  return u.b;
}

// ---------------- fill ----------------
__global__ void fill_k(unsigned* __restrict__ p, unsigned v, int n) {
  int i = blockIdx.x * 256 + threadIdx.x;
  if (i < n) p[i] = v;
}

// ---------------- embedding gather -> bf16 x [8192 rows=t*64+b][512] ----------------
__global__ __launch_bounds__(256) void xgather_k(const int* __restrict__ ids,
                                                 const float* __restrict__ emb,
                                                 unsigned short* __restrict__ xb) {
  int g = blockIdx.x * 256 + threadIdx.x;   // 8192 rows x 64 chunks of 8
  int r = g >> 6, c = g & 63;
  int t = r >> 6, b = r & 63;
  int id = ids[(size_t)b * T_SIZE + t];
  const float4* s4 = reinterpret_cast<const float4*>(emb + (size_t)id * H_SIZE + c * 8);
  float4 v0 = s4[0], v1 = s4[1];
  u16x8 o;
  o[0] = f2bf(v0.x); o[1] = f2bf(v0.y); o[2] = f2bf(v0.z); o[3] = f2bf(v0.w);
  o[4] = f2bf(v1.x); o[5] = f2bf(v1.y); o[6] = f2bf(v1.z); o[7] = f2bf(v1.w);
  *reinterpret_cast<u16x8*>(xb + (size_t)r * H_SIZE + c * 8) = o;
}

// ---------------- f32 [K][N] -> bf16 [N][K] transpose (64x64 tiles) ----------------
__global__ __launch_bounds__(256) void trans_k(const float* __restrict__ src,
                                               unsigned short* __restrict__ dst,
                                               int src_ld, int n_tiles) {
  __shared__ float tile[64][65];
  const int tid = threadIdx.x;
  const int kt = blockIdx.x / n_tiles, nt = blockIdx.x % n_tiles;
#pragma unroll
  for (int q = 0; q < 16; ++q) {
    int f = tid + 256 * q;
    int r = f >> 6, c = f & 63;
    tile[r][c] = src[(size_t)(kt * 64 + r) * src_ld + nt * 64 + c];
  }
  __syncthreads();
#pragma unroll
  for (int q = 0; q < 2; ++q) {
    int u = tid + 256 * q;
    int n = u >> 3, kg = u & 7;
    u16x8 o;
#pragma unroll
    for (int e = 0; e < 8; ++e) o[e] = f2bf(tile[kg * 8 + e][n]);
    *reinterpret_cast<u16x8*>(dst + (size_t)(nt * 64 + n) * 512 + kt * 64 + kg * 8) = o;
  }
}

// load 8 B-fragments (one K-half) for column vc from a [N][512] bf16 matrix
__device__ __forceinline__ void loadB8(bf16x8* p, const unsigned short* Wb,
                                       int vc, int kh, int kof) {
#pragma unroll
  for (int ks = 0; ks < 8; ++ks)
    p[ks] = *reinterpret_cast<const bf16x8*>(
        Wb + (size_t)vc * 512 + (kh * 8 + ks) * 32 + kof);
}

// ---------------- flag-gated dataflow MFMA 2-layer LSTM + input projection ----------------
// 64 blocks; block owns 8 h-cols of BOTH layers. LDS: W1x (32K) + W1r (32K)
// + W2 (64K) + 2 gate bufs (16K) = 144 KB. Per step t:
//   x-part MFMAs (poll-independent) | poll flags{h1[t-1], h2[t-2]} |
//   bulk-load h frags | L1(t) -> store h1[t] + flag | L2(t-1) -> store + flag
__global__ __launch_bounds__(RTH, 1) void recur_k(
    const float* __restrict__ W1, const float* __restrict__ W2,
    const float* __restrict__ b1, const float* __restrict__ b2,
    const unsigned short* __restrict__ xb,
    const unsigned short* __restrict__ hzero,
    unsigned short* __restrict__ h1all, unsigned short* __restrict__ h2all,
    int* __restrict__ flag1, int* __restrict__ flag2)
{
  __shared__ short wldsX[2 * 16 * 64 * 8];  // 32 KB  W1 x-slice (rows 0..511)
  __shared__ short wlds1[2 * 16 * 64 * 8];  // 32 KB  W1 recurrent slice (rows 512..1023)
  __shared__ short wlds2[2 * 32 * 64 * 8];  // 64 KB  W2 slice
  __shared__ float gbA[64][32];             // 8 KB   L1 gates
  __shared__ float gbB[64][32];             // 8 KB   L2 gates

  const int tid = threadIdx.x;
  const int bid = blockIdx.x;
  const int h0  = bid * 8;
  const int w   = tid >> 6, l = tid & 63;
  const int lane = tid & 63;

  // ---- one-time weight preload, bf16 in B-frag order ----
  {
    for (int idx = tid; idx < 2 * 16 * 64; idx += RTH) {
      int ln2 = idx & 63;
      int ks  = (idx >> 6) % 16;
      int ng  = (idx >> 6) / 16;
      int n   = ln2 & 15;
      int col = (n & 3) * H_SIZE + h0 + ng * 4 + (n >> 2);
      int kb  = ks * 32 + (ln2 >> 4) * 8;
      short* dX = &wldsX[((size_t)(ng * 16 + ks) * 64 + ln2) * 8];
      short* d1 = &wlds1[((size_t)(ng * 16 + ks) * 64 + ln2) * 8];
#pragma unroll
      for (int e = 0; e < 8; ++e) {
        dX[e] = (short)f2bf(W1[(size_t)(kb + e) * NG + col]);
        d1[e] = (short)f2bf(W1[(size_t)(H_SIZE + kb + e) * NG + col]);
      }
    }
    for (int idx = tid; idx < 2 * 32 * 64; idx += RTH) {
      int ln2 = idx & 63;
      int ks  = (idx >> 6) % 32;
      int ng  = (idx >> 6) / 32;
      int n   = ln2 & 15;
      int col = (n & 3) * H_SIZE + h0 + ng * 4 + (n >> 2);
      int kb  = ks * 32 + (ln2 >> 4) * 8;
      short* dst = &wlds2[((size_t)(ng * 32 + ks) * 64 + ln2) * 8];
#pragma unroll
      for (int e = 0; e < 8; ++e)
        dst[e] = (short)f2bf(W2[(size_t)(kb + e) * NG + col]);
    }
  }

  // pointwise mapping: thread = pb*4+pq handles (b=pb, cols h0+2pq, h0+2pq+1)
  const int pb = tid >> 2, pq = tid & 3;
  float c1[2] = {0.f, 0.f}, c2[2] = {0.f, 0.f};
  float bias1[2][4], bias2[2][4];
#pragma unroll
  for (int hh = 0; hh < 2; ++hh)
#pragma unroll
    for (int g = 0; g < 4; ++g) {
      bias1[hh][g] = b1[g * H_SIZE + h0 + 2 * pq + hh];
      bias2[hh][g] = b2[g * H_SIZE + h0 + 2 * pq + hh];
    }
  __syncthreads();

  const int arow = w * 16 + (l & 15);
  const int kof  = (l >> 4) * 8;

  for (int t = 0; t <= T_SIZE; ++t) {
    // ---- x-part of L1(t): independent of h -> fills the poll window ----
    f32x4 acc0 = {0.f, 0.f, 0.f, 0.f};
    f32x4 acc1 = {0.f, 0.f, 0.f, 0.f};
    if (t < T_SIZE) {
      const unsigned short* xr = xb + ((size_t)t * 64 + arow) * H_SIZE + kof;
#pragma unroll
      for (int ks = 0; ks < 16; ++ks) {
        bf16x8 avx = *reinterpret_cast<const bf16x8*>(xr + ks * 32);
        bf16x8 bv0 = *reinterpret_cast<const bf16x8*>(&wldsX[((size_t)(0 * 16 + ks) * 64 + l) * 8]);
        bf16x8 bv1 = *reinterpret_cast<const bf16x8*>(&wldsX[((size_t)(1 * 16 + ks) * 64 + l) * 8]);
        acc0 = __builtin_amdgcn_mfma_f32_16x16x32_bf16(avx, bv0, acc0, 0, 0, 0);
        acc1 = __builtin_amdgcn_mfma_f32_16x16x32_bf16(avx, bv1, acc1, 0, 0, 0);
      }
    }

    // ---- lightweight readiness poll: one 4B flag per lane ----
    {
      bool need1 = (t >= 1), need2 = (t >= 2);
      const int* f1p = flag1 + (size_t)(t - 1) * 64 + lane;
      const int* f2p = flag2 + (size_t)(t - 2) * 64 + lane;
      while (need1 | need2) {
        if (need1 && __hip_atomic_load(f1p, __ATOMIC_RELAXED, __HIP_MEMORY_SCOPE_AGENT))
          need1 = false;
        if (need2 && __hip_atomic_load(f2p, __ATOMIC_RELAXED, __HIP_MEMORY_SCOPE_AGENT))
          need2 = false;
        if (need1 | need2) __builtin_amdgcn_s_sleep(1);
      }
    }
    __syncthreads();   // all 64 flags observed across lanes

    // ---- bulk data loads (exactly once) ----
    const unsigned short* h1src = ((t == 0) ? hzero : h1all + (size_t)(t - 1) * HB)
                                  + (size_t)arow * H_SIZE + kof;
    const unsigned short* h2src = ((t < 2) ? hzero : h2all + (size_t)(t - 2) * HB)
                                  + (size_t)arow * H_SIZE + kof;
    bf16x8 av1[16], av2[16];
#pragma unroll
    for (int ks = 0; ks < 16; ++ks) av1[ks] = aload16(h1src + ks * 32);
#pragma unroll
    for (int ks = 0; ks < 16; ++ks) av2[ks] = aload16(h2src + ks * 32);

    // ================= L1(t): h-part MFMA + pointwise + store + flag =================
    if (t < T_SIZE) {
#pragma unroll
      for (int ks = 0; ks < 16; ++ks) {
        bf16x8 bv0 = *reinterpret_cast<const bf16x8*>(&wlds1[((size_t)(0 * 16 + ks) * 64 + l) * 8]);
        bf16x8 bv1 = *reinterpret_cast<const bf16x8*>(&wlds1[((size_t)(1 * 16 + ks) * 64 + l) * 8]);
        acc0 = __builtin_amdgcn_mfma_f32_16x16x32_bf16(av1[ks], bv0, acc0, 0, 0, 0);
        acc1 = __builtin_amdgcn_mfma_f32_16x16x32_bf16(av1[ks], bv1, acc1, 0, 0, 0);
      }
      {
        const int crow = w * 16 + ((l >> 4) << 2);
        const int ccol = l & 15;
#pragma unroll
        for (int r = 0; r < 4; ++r) {
          gbA[crow + r][ccol]      = acc0[r];
          gbA[crow + r][16 + ccol] = acc1[r];
        }
      }
      __syncthreads();
      unsigned short hbv[2];
#pragma unroll
      for (int hh = 0; hh < 2; ++hh) {
        const int hl = 2 * pq + hh;
        const int ng = hl >> 2, jj = hl & 3;
        float g[4];
#pragma unroll
        for (int gg = 0; gg < 4; ++gg)
          g[gg] = gbA[pb][ng * 16 + jj * 4 + gg] + bias1[hh][gg];
        float cn = c1[hh] * sigf(g[2]) + sigf(g[0]) * tanhf_fast(g[1]);
        float hn = tanhf_fast(cn) * sigf(g[3]);
        c1[hh] = cn;
        hbv[hh] = f2bf(hn);
      }
      unsigned pack = (unsigned)hbv[0] | ((unsigned)hbv[1] << 16);
      __hip_atomic_store((unsigned*)(h1all + (size_t)t * HB + (size_t)pb * H_SIZE
                                     + h0 + 2 * pq),
                         pack, __ATOMIC_RELAXED, __HIP_MEMORY_SCOPE_AGENT);
      __syncthreads();   // drain all threads' h1 stores
      if (tid == 0)
        __hip_atomic_store(&flag1[(size_t)t * 64 + bid], 1, __ATOMIC_RELAXED,
                           __HIP_MEMORY_SCOPE_AGENT);
    }

    // ================= L2(t-1): MFMA + pointwise + store + flag =================
    if (t >= 1) {
      f32x4 bcc0 = {0.f, 0.f, 0.f, 0.f};
      f32x4 bcc1 = {0.f, 0.f, 0.f, 0.f};
#pragma unroll
      for (int ks = 0; ks < 16; ++ks) {   // h2[t-2] rows 512..1023
        bf16x8 bv0 = *reinterpret_cast<const bf16x8*>(&wlds2[((size_t)(0 * 32 + 16 + ks) * 64 + l) * 8]);
        bf16x8 bv1 = *reinterpret_cast<const bf16x8*>(&wlds2[((size_t)(1 * 32 + 16 + ks) * 64 + l) * 8]);
        bcc0 = __builtin_amdgcn_mfma_f32_16x16x32_bf16(av2[ks], bv0, bcc0, 0, 0, 0);
        bcc1 = __builtin_amdgcn_mfma_f32_16x16x32_bf16(av2[ks], bv1, bcc1, 0, 0, 0);
      }
#pragma unroll
      for (int ks = 0; ks < 16; ++ks) {   // h1[t-1] rows 0..511
        bf16x8 bv0 = *reinterpret_cast<const bf16x8*>(&wlds2[((size_t)(0 * 32 + ks) * 64 + l) * 8]);
        bf16x8 bv1 = *reinterpret_cast<const bf16x8*>(&wlds2[((size_t)(1 * 32 + ks) * 64 + l) * 8]);
        bcc0 = __builtin_amdgcn_mfma_f32_16x16x32_bf16(av1[ks], bv0, bcc0, 0, 0, 0);
        bcc1 = __builtin_amdgcn_mfma_f32_16x16x32_bf16(av1[ks], bv1, bcc1, 0, 0, 0);
      }
      {
        const int crow = w * 16 + ((l >> 4) << 2);
        const int ccol = l & 15;
#pragma unroll
        for (int r = 0; r < 4; ++r) {
          gbB[crow + r][ccol]      = bcc0[r];
          gbB[crow + r][16 + ccol] = bcc1[r];
        }
      }
      __syncthreads();
      unsigned short hbv[2];
#pragma unroll
      for (int hh = 0; hh < 2; ++hh) {
        const int hl = 2 * pq + hh;
        const int ng = hl >> 2, jj = hl & 3;
        float g[4];
#pragma unroll
        for (int gg = 0; gg < 4; ++gg)
          g[gg] = gbB[pb][ng * 16 + jj * 4 + gg] + bias2[hh][gg];
        float cn = c2[hh] * sigf(g[2]) + sigf(g[0]) * tanhf_fast(g[1]);
        float hn = tanhf_fast(cn) * sigf(g[3]);
        c2[hh] = cn;
        hbv[hh] = f2bf(hn);
      }
      unsigned pack = (unsigned)hbv[0] | ((unsigned)hbv[1] << 16);
      __hip_atomic_store((unsigned*)(h2all + (size_t)(t - 1) * HB
                                     + (size_t)pb * H_SIZE + h0 + 2 * pq),
                         pack, __ATOMIC_RELAXED, __HIP_MEMORY_SCOPE_AGENT);
      __syncthreads();   // drain h2 stores + protect gbB
      if (tid == 0)
        __hip_atomic_store(&flag2[(size_t)(t - 1) * 64 + bid], 1, __ATOMIC_RELAXED,
                           __HIP_MEMORY_SCOPE_AGENT);
    }
  }
}

// ---------------- MFMA fused logits + online logsumexp (8 waves/block) ----------------
// grid 256: bx = t*2 + half. 8 waves: wr=w&3 row-group, wq=w>>2 col-half.
__global__ __launch_bounds__(512) void ce_mfma_k(const unsigned short* __restrict__ outs,
                                                 const unsigned short* __restrict__ Wvb,
                                                 const float* __restrict__ bvb,
                                                 const int* __restrict__ tgts,
                                                 float* __restrict__ pmx,
                                                 float* __restrict__ psm,
                                                 float* __restrict__ ptg) {
  const int tid = threadIdx.x;
  const int t = blockIdx.x >> 1, half = blockIdx.x & 1;
  const int w = tid >> 6, l = tid & 63;
  const int wr = w & 3, wq = w >> 2;
  const int m0 = wr * 16;
  const int kof = (l >> 4) * 8;
  const int ln = l & 15;
  const int c0 = half * 4000 + wq * 2000;
  bf16x8 av[16];
#pragma unroll
  for (int ks = 0; ks < 16; ++ks)
    av[ks] = *reinterpret_cast<const bf16x8*>(
        outs + ((size_t)t * 64 + m0 + ln) * H_SIZE + ks * 32 + kof);
  int lbl[4];
#pragma unroll
  for (int r = 0; r < 4; ++r)
    lbl[r] = tgts[(size_t)(m0 + ((l >> 4) << 2) + r) * T_SIZE + t];

  float mx[4] = {-1e30f, -1e30f, -1e30f, -1e30f};
  float sm[4] = {0.f, 0.f, 0.f, 0.f};
  float tg[4] = {0.f, 0.f, 0.f, 0.f};

  bf16x8 p0[8], p1[8];
  loadB8(p0, Wvb, c0 + ln, 0, kof);
  for (int ct = 0; ct < 125; ++ct) {
    const int vc = c0 + ct * 16 + ln;
    const int vcn = c0 + ((ct < 124) ? ct + 1 : ct) * 16 + ln;
    f32x4 acc = {0.f, 0.f, 0.f, 0.f};
    loadB8(p1, Wvb, vc, 1, kof);
#pragma unroll
    for (int ks = 0; ks < 8; ++ks)
      acc = __builtin_amdgcn_mfma_f32_16x16x32_bf16(av[ks], p0[ks], acc, 0, 0, 0);
    loadB8(p0, Wvb, vcn, 0, kof);
#pragma unroll
    for (int ks = 0; ks < 8; ++ks)
      acc = __builtin_amdgcn_mfma_f32_16x16x32_bf16(av[8 + ks], p1[ks], acc, 0, 0, 0);

    float bb = bvb[vc];
#pragma unroll
    for (int r = 0; r < 4; ++r) {
      float lg = acc[r] + bb;
      tg[r] += (vc == lbl[r]) ? lg : 0.f;
      float nm = fmaxf(mx[r], lg);
      sm[r] = sm[r] * __expf(mx[r] - nm) + __expf(lg - nm);
      mx[r] = nm;
    }
  }

#pragma unroll
  for (int off = 1; off <= 8; off <<= 1) {
#pragma unroll
    for (int r = 0; r < 4; ++r) {
      float om = __shfl_xor(mx[r], off, 64);
      float os = __shfl_xor(sm[r], off, 64);
      float ot = __shfl_xor(tg[r], off, 64);
      float nm = fmaxf(mx[r], om);
      sm[r] = sm[r] * __expf(mx[r] - nm) + os * __expf(om - nm);
      mx[r] = nm;
      tg[r] += ot;
    }
  }
  if (ln == 0) {
    int idx = ((int)blockIdx.x * 2 + wq) * 64 + m0 + ((l >> 4) << 2);
#pragma unroll
    for (int r = 0; r < 4; ++r) {
      pmx[idx + r] = mx[r]; psm[idx + r] = sm[r]; ptg[idx + r] = tg[r];
    }
  }
}

// ---------------- merge 4 partials, per-row loss, sum ----------------
__global__ __launch_bounds__(256) void cemerge_k(const float* __restrict__ pmx,
                                                 const float* __restrict__ psm,
                                                 const float* __restrict__ ptg,
                                                 float* __restrict__ accum) {
  int g = blockIdx.x * 256 + threadIdx.x;   // 0..8191
  int t = g >> 6, row = g & 63;
  float M = -1e30f, S = 0.f, T = 0.f;
#pragma unroll
  for (int j = 0; j < 4; ++j) {
    int i = (t * 4 + j) * 64 + row;
    float m = pmx[i], s = psm[i];
    float nm = fmaxf(M, m);
    S = S * __expf(M - nm) + s * __expf(m - nm);
    M = nm;
    T += ptg[i];
  }
  float loss = M + logf(S) - T;
#pragma unroll
  for (int off = 32; off >= 1; off >>= 1)
    loss += __shfl_xor(loss, off, 64);
  if ((threadIdx.x & 63) == 0) atomicAdd(accum, loss);
}

__global__ void finish_k(const float* __restrict__ accum, float* __restrict__ out) {
  out[0] = accum[0] * (1.f / (float)NROW);
}

// ---------------- launcher ----------------
extern "C" void kernel_launch(void* const* d_in, const int* in_sizes, int n_in,
                              void* d_out, int out_size, void* d_ws, size_t ws_size,
                              hipStream_t stream) {
  const int*   ids  = (const int*)  d_in[0];
  const int*   tgts = (const int*)  d_in[1];
  const float* emb  = (const float*)d_in[2];
  const float* W1   = (const float*)d_in[3];
  const float* b1   = (const float*)d_in[4];
  const float* W2   = (const float*)d_in[5];
  const float* b2   = (const float*)d_in[6];
  const float* Wv   = (const float*)d_in[7];
  const float* bv   = (const float*)d_in[8];
  float* out = (float*)d_out;

  // ws layout (bytes), total ~33.9 MB:
  char* ws = (char*)d_ws;
  unsigned short* xb    = (unsigned short*)(ws);                 //  8,388,608
  unsigned short* outsb = (unsigned short*)(ws + 8388608);       //  8,388,608 (=h2all)
  unsigned short* h1all = (unsigned short*)(ws + 16777216);      //  8,388,608
  unsigned short* Wvb   = (unsigned short*)(ws + 25165824);      //  8,192,000
  unsigned short* hzero = (unsigned short*)(ws + 33357824);      //     65,536
  int*            flag1 = (int*)           (ws + 33423360);      //     32,768
  int*            flag2 = (int*)           (ws + 33456128);      //     32,768
  float*          accum = (float*)         (ws + 33488896);      //          4
  float*          pmx   = (float*)         (ws + 33488960);      //    131,072
  float*          psm   = (float*)         (ws + 33620032);      //    131,072
  float*          ptg   = (float*)         (ws + 33751104);      //    131,072

  // zero hzero + flag1 + flag2 + accum (contiguous span, 32769 u32)
  fill_k<<<129, 256, 0, stream>>>((unsigned*)hzero, 0u, 32769);

  xgather_k<<<2048, 256, 0, stream>>>(ids, emb, xb);
  trans_k<<<1000, 256, 0, stream>>>(Wv, Wvb, V_SIZE, 125);    // Wv -> Wvb

  {
    void* args[] = { (void*)&W1, (void*)&W2, (void*)&b1, (void*)&b2,
                     (void*)&xb, (void*)&hzero, (void*)&h1all, (void*)&outsb,
                     (void*)&flag1, (void*)&flag2 };
    hipError_t e = hipLaunchCooperativeKernel((const void*)recur_k,
                                              dim3(RBLK), dim3(RTH),
                                              args, 0, stream);
    if (e != hipSuccess) {
      // plain launch: 64 blocks on 256 CUs -> co-resident
      recur_k<<<dim3(RBLK), dim3(RTH), 0, stream>>>(W1, W2, b1, b2, xb, hzero,
                                                    h1all, outsb, flag1, flag2);
    }
  }

  ce_mfma_k<<<256, 512, 0, stream>>>(outsb, Wvb, bv, tgts, pmx, psm, ptg);
  cemerge_k<<<32, 256, 0, stream>>>(pmx, psm, ptg, accum);
  finish_k<<<1, 1, 0, stream>>>(accum, out);
}